// Round 16
// baseline (101.163 us; speedup 1.0000x reference)
//
#include <hip/hip_runtime.h>

typedef __bf16 bf16x8 __attribute__((ext_vector_type(8)));
typedef float f32x4 __attribute__((ext_vector_type(4)));
typedef unsigned short u16;
typedef unsigned int u32;
typedef u16 u16x8 __attribute__((ext_vector_type(8)));
typedef u16 u16x4 __attribute__((ext_vector_type(4)));
typedef u32 u32x4 __attribute__((ext_vector_type(4)));

__device__ __forceinline__ u16 f2bf(float f) {
    u32 u = __builtin_bit_cast(u32, f);
    u += 0x7fffu + ((u >> 16) & 1u);   // RNE
    return (u16)(u >> 16);
}
__device__ __forceinline__ float bf2f(u16 v) {
    return __builtin_bit_cast(float, (u32)v << 16);
}
__device__ __forceinline__ u32 cvtpk(float a, float b) {   // lo=bf16(a), hi=bf16(b)
    u32 d;
    asm("v_cvt_pk_bf16_f32 %0, %1, %2" : "=v"(d) : "v"(a), "v"(b));
    return d;
}
__device__ __forceinline__ f32x4 mfma16(u16x8 a, u16x8 b, f32x4 c) {
    return __builtin_amdgcn_mfma_f32_16x16x32_bf16(
        __builtin_bit_cast(bf16x8, a), __builtin_bit_cast(bf16x8, b), c, 0, 0, 0);
}

#define GLOAD16(SRC, DST)                                                     \
    __builtin_amdgcn_global_load_lds(                                         \
        (const __attribute__((address_space(1))) unsigned int*)(SRC),         \
        (__attribute__((address_space(3))) unsigned int*)(DST), 16, 0, 0)

// chunk-XOR LDS addressing for a [16][128] u16 tile (16B chunks, XOR row into chunk)
__device__ __forceinline__ int ldsAddr(int r, int c) {       // u16 index
    return r * 128 + (((c >> 3) ^ (r & 7)) << 3) + (c & 7);
}

// ---------------------------------------------------------------------------
// Kernel 0: fused prep. Blocks [0,1024): x fp32 -> xf frag-major bf16.
// Blocks [1024,1120): W fp32 [512][128] -> Wf frag-major bf16
// (Wq pre-scaled by 1/sqrt(128)*log2(e) for log2-domain softmax).
// ---------------------------------------------------------------------------
__global__ __launch_bounds__(256) void prep_all(
    const float* __restrict__ x,
    const float* __restrict__ Wq, const float* __restrict__ Wk,
    const float* __restrict__ Wv,
    u16* __restrict__ xf, u16* __restrict__ wf)
{
    __shared__ u16 T[16 * 512];
    const int t = threadIdx.x;
    if (blockIdx.x < 1024) {
        const int rb = blockIdx.x;
        const int row = t >> 4, colb = (t & 15) * 32;
        const float* src = x + (size_t)(rb * 16 + row) * 512 + colb;
        #pragma unroll
        for (int i = 0; i < 4; ++i) {
            float4 va = *(const float4*)(src + i * 8);
            float4 vb = *(const float4*)(src + i * 8 + 4);
            u16x8 v;
            v[0] = f2bf(va.x); v[1] = f2bf(va.y); v[2] = f2bf(va.z); v[3] = f2bf(va.w);
            v[4] = f2bf(vb.x); v[5] = f2bf(vb.y); v[6] = f2bf(vb.z); v[7] = f2bf(vb.w);
            int chunk = ((colb >> 3) + i) ^ (row & 7);
            *(u16x8*)&T[row * 512 + chunk * 8] = v;
        }
        __syncthreads();
        #pragma unroll
        for (int ii = 0; ii < 4; ++ii) {
            int flatF = ii * 256 + t;
            int ds = flatF >> 6, lane = flatF & 63;
            int l16 = lane & 15, g = lane >> 4;
            int chunk = (4 * ds + g) ^ (l16 & 7);
            u16x8 v = *(const u16x8*)&T[l16 * 512 + chunk * 8];
            *(u16x8*)&xf[(((size_t)rb * 16 + ds) * 64 + lane) * 8] = v;
        }
    } else {
        int flat = (blockIdx.x - 1024) * 256 + t;      // [0, 24576)
        int widx = flat >> 13, rem = flat & 8191;
        int n = rem >> 10, ds = (rem >> 6) & 15, lane = rem & 63;
        int l16 = lane & 15, g = lane >> 4;
        const float* W = (widx == 0) ? Wq : (widx == 1 ? Wk : Wv);
        const float sc = (widx == 0) ? (0.08838834764831845f * 1.4426950408889634f) : 1.0f;
        u16x8 v;
        #pragma unroll
        for (int j = 0; j < 8; ++j)
            v[j] = f2bf(W[(size_t)(ds * 32 + 8 * g + j) * 128 + n * 16 + l16] * sc);
        *(u16x8*)&wf[(size_t)flat * 8] = v;
    }
}

// ---------------------------------------------------------------------------
// Kernel 1: QKV GEMM with LDS-staged W slices (round-13, measured good).
// Block = 4 waves x 16 rows; grid (256, 3) = 768 blocks -> 3 blocks/CU.
// ---------------------------------------------------------------------------
__global__ __launch_bounds__(256, 3) void qkv2(
    const u16* __restrict__ xf, const u16* __restrict__ wf,
    u16* __restrict__ Qf, u16* __restrict__ Kf, u16* __restrict__ Vf)
{
    __shared__ u16 Wbuf[2][4096];    // [buf][n*64+lane -> 8 u16]  (8 KB each)
    __shared__ u16 T4[4][16 * 128];
    const int tid = threadIdx.x, lane = tid & 63, wid = tid >> 6;
    const int g = lane >> 4, l16 = lane & 15;
    const int widx = blockIdx.y;
    const int rbg = blockIdx.x * 4 + wid;        // 16-row block [0,1024)
    const u16* WfB = wf + (size_t)widx * 65536;
    u16* T = T4[wid];

    GLOAD16(WfB + (size_t)((wid * 16 + 0) * 64 + lane) * 8,
            Wbuf[0] + (wid * 64 + lane) * 8);
    GLOAD16(WfB + (size_t)(((wid + 4) * 16 + 0) * 64 + lane) * 8,
            Wbuf[0] + ((wid + 4) * 64 + lane) * 8);

    const f32x4 fz = {0.f, 0.f, 0.f, 0.f};
    f32x4 acc[8];
    #pragma unroll
    for (int n = 0; n < 8; ++n) acc[n] = fz;

    u16x8 a_cur = *(const u16x8*)&xf[(((size_t)rbg * 16 + 0) * 64 + lane) * 8];
    __syncthreads();                              // slice 0 staged

    #pragma unroll 1
    for (int ds = 0; ds < 16; ++ds) {
        u16x8 a_next;
        if (ds + 1 < 16) {
            const int nds = ds + 1, bb = nds & 1;
            GLOAD16(WfB + (size_t)((wid * 16 + nds) * 64 + lane) * 8,
                    Wbuf[bb] + (wid * 64 + lane) * 8);
            GLOAD16(WfB + (size_t)(((wid + 4) * 16 + nds) * 64 + lane) * 8,
                    Wbuf[bb] + ((wid + 4) * 64 + lane) * 8);
            a_next = *(const u16x8*)&xf[(((size_t)rbg * 16 + nds) * 64 + lane) * 8];
        }
        const u16* Wl = Wbuf[ds & 1];
        #pragma unroll
        for (int n = 0; n < 8; ++n) {
            u16x8 b = *(const u16x8*)&Wl[(n * 64 + lane) * 8];
            acc[n] = mfma16(a_cur, b, acc[n]);
        }
        __syncthreads();
        if (ds + 1 < 16) a_cur = a_next;
    }

    #pragma unroll
    for (int n = 0; n < 8; ++n) {
        #pragma unroll
        for (int r = 0; r < 4; ++r)
            T[ldsAddr(4 * g + r, n * 16 + l16)] = f2bf(acc[n][r]);
    }
    if (widx < 2) {
        u16* dst = (widx == 0) ? Qf : Kf;
        #pragma unroll
        for (int ds = 0; ds < 4; ++ds) {
            int chunk = (4 * ds + g) ^ (l16 & 7);
            u16x8 v = *(const u16x8*)&T[l16 * 128 + chunk * 8];
            *(u16x8*)&dst[(((size_t)rbg * 4 + ds) * 64 + lane) * 8] = v;
        }
    } else {
        const int kb = rbg >> 2, ksel = (rbg >> 1) & 1, g0 = (rbg & 1) * 2;
        #pragma unroll
        for (int s = 0; s < 4; ++s) {
            int flat = s * 64 + lane;
            int e = flat >> 5, gg = (flat >> 4) & 1, l16p = flat & 15;
            u16x8 v;
            #pragma unroll
            for (int j = 0; j < 8; ++j)
                v[j] = T[ldsAddr(8 * gg + j, e * 16 + l16p)];
            *(u16x8*)&Vf[((((size_t)kb * 2 + ksel) * 8 + e) * 64
                          + (g0 + gg) * 16 + l16p) * 8] = v;
        }
    }
}

// ---------------------------------------------------------------------------
// Kernel 2: causal flash attention with 3-deep LDS ring + counted vmcnt.
// Same job decode / softmax / MFMA structure as round 12; the only change:
// prefetch distance 2, raw s_barrier with s_waitcnt vmcnt(8) so the
// just-issued global_load_lds stay in flight across the barrier (T4).
// LDS = 3x16KB ring + 16KB pad = 64KB -> pinned 2 blocks/CU (L2 wall).
// ---------------------------------------------------------------------------
__global__ __launch_bounds__(256, 2) void attn8(
    const u16* __restrict__ Qf, const u16* __restrict__ Kf,
    const u16* __restrict__ Vf, float* __restrict__ out,
    u16* __restrict__ po, float* __restrict__ pml, int split)
{
    __shared__ u16 lds[3][16384];   // ring: [ K 16KB | V 16KB ] per slot
    __shared__ u16 ldspad[8192];    // pad to 64 KB total -> 2 blocks/CU
    const int tid = threadIdx.x, lane = tid & 63, wid = tid >> 6;
    const int g = lane >> 4, l16 = lane & 15;
    if (split == -12345) ldspad[tid] = 0;   // runtime-opaque: keep pad allocated

    int b, qb, c, u;
    if (split) {
        const int xcd = blockIdx.x & 7;        // XCD pair {2b,2b+1} -> batch b
        b = xcd >> 1;
        int jb = 271 - ((xcd & 1) * 136 + (blockIdx.x >> 3));   // longest-first
        u = 0;
        while ((u + 1) * (u + 2) <= jb) ++u;   // u(u+1) <= jb < (u+1)(u+2)
        int r = jb - u * (u + 1);
        int hi = (r >= u + 1) ? 1 : 0;
        qb = 2 * u + hi;
        c = r - hi * (u + 1);
    } else {
        b = blockIdx.x & 3;
        qb = blockIdx.x >> 2;
        c = 0; u = 0;
    }
    const int q0 = qb * 128 + wid * 32;        // wave's first q row
    const int k_lo = c * 256;
    const int k_hi = min(k_lo + (split ? 256 : 4096), qb * 128 + 128);
    const int nch = u + 1;
    const int wklen = q0 + 32;                 // wave needs tiles with k0 < wklen
    const int nt = (k_hi - k_lo) >> 6;         // 64-key tiles in this job (>=2)

    // prologue: stage tiles 0,1 into ring slots 0,1 + load Q fragments
    {
        const u16* src0;
        if (wid < 2) src0 = Kf + (size_t)(b * 256 + (k_lo >> 4)) * 2048 + wid * 4096;
        else         src0 = Vf + (size_t)(b * 64 + (k_lo >> 6)) * 8192 + (wid - 2) * 4096;
        u16* dst0 = &lds[0][wid * 4096];
        #pragma unroll
        for (int j = 0; j < 8; ++j)
            GLOAD16(src0 + j * 512 + lane * 8, dst0 + j * 512);
        if (nt > 1) {
            const int k1 = k_lo + 64;
            const u16* src1;
            if (wid < 2) src1 = Kf + (size_t)(b * 256 + (k1 >> 4)) * 2048 + wid * 4096;
            else         src1 = Vf + (size_t)(b * 64 + (k1 >> 6)) * 8192 + (wid - 2) * 4096;
            u16* dst1 = &lds[1][wid * 4096];
            #pragma unroll
            for (int j = 0; j < 8; ++j)
                GLOAD16(src1 + j * 512 + lane * 8, dst1 + j * 512);
        }
    }
    const int rbq = b * 256 + qb * 8 + wid * 2;
    u16x8 qf0[4], qf1[4];
    #pragma unroll
    for (int ds = 0; ds < 4; ++ds) {
        qf0[ds] = *(const u16x8*)&Qf[(((size_t)rbq * 4 + ds) * 64 + lane) * 8];
        qf1[ds] = *(const u16x8*)&Qf[(((size_t)(rbq + 1) * 4 + ds) * 64 + lane) * 8];
    }

    const f32x4 fz = {0.f, 0.f, 0.f, 0.f};
    f32x4 o0[8], o1[8];
    #pragma unroll
    for (int e = 0; e < 8; ++e) { o0[e] = fz; o1[e] = fz; }
    float l0 = 0.f, l1 = 0.f;                  // per-lane partial denominators

    const int srcA = l16 + ((g & 1) << 5);
    const int srcB = srcA + 16;
    const bool hiSel = (g >= 2);

    __syncthreads();                            // full drain once (tiles 0,1 + Q)

    int bi = 0;
    #pragma unroll 1
    for (int it = 0; it < nt; ++it) {
        const int k0 = k_lo + (it << 6);
        const bool pf = (it + 2 < nt);
        // ---- prefetch tile it+2 into ring slot bi+2 (mod 3) ----
        if (pf) {
            const int kn = k0 + 128;
            int pi = bi + 2; if (pi >= 3) pi -= 3;
            const u16* src;
            if (wid < 2) src = Kf + (size_t)(b * 256 + (kn >> 4)) * 2048 + wid * 4096;
            else         src = Vf + (size_t)(b * 64 + (kn >> 6)) * 8192 + (wid - 2) * 4096;
            u16* dst = &lds[pi][wid * 4096];
            #pragma unroll
            for (int j = 0; j < 8; ++j)
                GLOAD16(src + j * 512 + lane * 8, dst + j * 512);
        }
        if (k0 < wklen) {
            const u16* Kl = &lds[bi][0];
            const u16* Vl = &lds[bi][8192];
            // ---- S^T = K * Q^T for both q-halves (K frags shared) ----
            f32x4 st0[4], st1[4];
            __builtin_amdgcn_s_setprio(1);
            #pragma unroll
            for (int kt = 0; kt < 4; ++kt) {
                st0[kt] = fz; st1[kt] = fz;
                #pragma unroll
                for (int ds = 0; ds < 4; ++ds) {
                    u16x8 kf = *(const u16x8*)&Kl[(kt * 4 + ds) * 512 + lane * 8];
                    st0[kt] = mfma16(kf, qf0[ds], st0[kt]);
                    st1[kt] = mfma16(kf, qf1[ds], st1[kt]);
                }
            }
            __builtin_amdgcn_s_setprio(0);
            // ---- causal mask (diagonal tiles only), per half ----
            if (k0 + 63 > q0) {
                int qg = q0 + l16;
                #pragma unroll
                for (int kt = 0; kt < 4; ++kt)
                    #pragma unroll
                    for (int r = 0; r < 4; ++r)
                        if (k0 + kt * 16 + g * 4 + r > qg) st0[kt][r] = -1e30f;
            }
            if (k0 + 63 > q0 + 16) {
                int qg = q0 + 16 + l16;
                #pragma unroll
                for (int kt = 0; kt < 4; ++kt)
                    #pragma unroll
                    for (int r = 0; r < 4; ++r)
                        if (k0 + kt * 16 + g * 4 + r > qg) st1[kt][r] = -1e30f;
            }
            // ---- unnormalized softmax: p = exp2(st), per-lane l accumulate ----
            u32 pk0[4][2], pk1[4][2];
            #pragma unroll
            for (int kt = 0; kt < 4; ++kt) {
                float p0 = exp2f(st0[kt][0]), p1 = exp2f(st0[kt][1]);
                float p2 = exp2f(st0[kt][2]), p3 = exp2f(st0[kt][3]);
                l0 += (p0 + p1) + (p2 + p3);
                pk0[kt][0] = cvtpk(p0, p1);
                pk0[kt][1] = cvtpk(p2, p3);
                float q0v = exp2f(st1[kt][0]), q1v = exp2f(st1[kt][1]);
                float q2v = exp2f(st1[kt][2]), q3v = exp2f(st1[kt][3]);
                l1 += (q0v + q1v) + (q2v + q3v);
                pk1[kt][0] = cvtpk(q0v, q1v);
                pk1[kt][1] = cvtpk(q2v, q3v);
            }
            // ---- P redistribute (in-register) + O^T += V^T * P^T ----
            #pragma unroll
            for (int ksel = 0; ksel < 2; ++ksel) {
                u32 a0 = __shfl((int)pk0[2 * ksel][0], srcA), b0 = __shfl((int)pk0[2 * ksel + 1][0], srcA);
                u32 a1 = __shfl((int)pk0[2 * ksel][1], srcA), b1 = __shfl((int)pk0[2 * ksel + 1][1], srcA);
                u32 a2 = __shfl((int)pk0[2 * ksel][0], srcB), b2 = __shfl((int)pk0[2 * ksel + 1][0], srcB);
                u32 a3 = __shfl((int)pk0[2 * ksel][1], srcB), b3 = __shfl((int)pk0[2 * ksel + 1][1], srcB);
                u32x4 d0 = { hiSel ? b0 : a0, hiSel ? b1 : a1, hiSel ? b2 : a2, hiSel ? b3 : a3 };
                u16x8 pf0 = __builtin_bit_cast(u16x8, d0);
                u32 c0 = __shfl((int)pk1[2 * ksel][0], srcA), e0 = __shfl((int)pk1[2 * ksel + 1][0], srcA);
                u32 c1 = __shfl((int)pk1[2 * ksel][1], srcA), e1 = __shfl((int)pk1[2 * ksel + 1][1], srcA);
                u32 c2 = __shfl((int)pk1[2 * ksel][0], srcB), e2 = __shfl((int)pk1[2 * ksel + 1][0], srcB);
                u32 c3 = __shfl((int)pk1[2 * ksel][1], srcB), e3 = __shfl((int)pk1[2 * ksel + 1][1], srcB);
                u32x4 d1 = { hiSel ? e0 : c0, hiSel ? e1 : c1, hiSel ? e2 : c2, hiSel ? e3 : c3 };
                u16x8 pf1 = __builtin_bit_cast(u16x8, d1);
                __builtin_amdgcn_s_setprio(1);
                #pragma unroll
                for (int e = 0; e < 8; ++e) {
                    u16x8 vf = *(const u16x8*)&Vl[(ksel * 8 + e) * 512 + lane * 8];
                    o0[e] = mfma16(vf, pf0, o0[e]);
                    o1[e] = mfma16(vf, pf1, o1[e]);
                }
                __builtin_amdgcn_s_setprio(0);
            }
        }
        // ---- counted-vmcnt barrier: keep just-issued prefetch in flight ----
        if (pf) {
            asm volatile("s_waitcnt vmcnt(8) lgkmcnt(0)" ::: "memory");
        } else {
            asm volatile("s_waitcnt vmcnt(0) lgkmcnt(0)" ::: "memory");
        }
        __builtin_amdgcn_s_barrier();
        __builtin_amdgcn_sched_barrier(0);
        bi = (bi == 2) ? 0 : bi + 1;
    }

    // reduce per-lane denominators across the 4 k-groups (once per block)
    l0 += __shfl_xor(l0, 16); l0 += __shfl_xor(l0, 32);
    l1 += __shfl_xor(l1, 16); l1 += __shfl_xor(l1, 32);

    if (nch == 1) {
        float inv0 = 1.0f / l0, inv1 = 1.0f / l1;
        float* op0 = out + ((size_t)b * 4096 + q0 + l16) * 128;
        float* op1 = out + ((size_t)b * 4096 + q0 + 16 + l16) * 128;
        #pragma unroll
        for (int e = 0; e < 8; ++e) {
            f32x4 v0 = o0[e], v1 = o1[e];
            #pragma unroll
            for (int r = 0; r < 4; ++r) { v0[r] *= inv0; v1[r] *= inv1; }
            *(f32x4*)&op0[e * 16 + g * 4] = v0;
            *(f32x4*)&op1[e * 16 + g * 4] = v1;
        }
    } else {
        const int slot = b * 272 + u * (u + 1) + (qb & 1) * (u + 1) + c;
        u16* pp0 = po + ((size_t)slot * 128 + wid * 32 + l16) * 128;
        u16* pp1 = pp0 + 16 * 128;
        #pragma unroll
        for (int e = 0; e < 8; ++e) {
            u16x4 v0, v1;
            #pragma unroll
            for (int r = 0; r < 4; ++r) { v0[r] = f2bf(o0[e][r]); v1[r] = f2bf(o1[e][r]); }
            *(u16x4*)&pp0[e * 16 + g * 4] = v0;
            *(u16x4*)&pp1[e * 16 + g * 4] = v1;
        }
        if (g == 0) {
            pml[(size_t)slot * 128 + wid * 32 + l16] = l0;
            pml[(size_t)slot * 128 + wid * 32 + 16 + l16] = l1;
        }
    }
}

// ---------------------------------------------------------------------------
// Kernel 3: merge split-K partials (qb >= 2). Plain sums (no max logic).
// ---------------------------------------------------------------------------
__global__ __launch_bounds__(256) void merge6(
    const u16* __restrict__ po, const float* __restrict__ pml,
    float* __restrict__ out)
{
    int gid = blockIdx.x * 256 + threadIdx.x;   // 491,520 total
    int colg = gid & 31;
    int rowid = gid >> 5;                        // [0, 15360)
    int b = rowid / 3840;
    int rr = rowid - b * 3840;
    int qb = (rr >> 7) + 2;
    int qr = rr & 127;
    int u = qb >> 1;
    int nch = u + 1;
    int slot0 = b * 272 + u * (u + 1) + (qb & 1) * (u + 1);

    float den = 0.f;
    f32x4 num = {0.f, 0.f, 0.f, 0.f};
    #pragma unroll 1
    for (int cc = 0; cc < nch; ++cc) {
        den += pml[(size_t)(slot0 + cc) * 128 + qr];
        u16x4 pv = *(const u16x4*)&po[((size_t)(slot0 + cc) * 128 + qr) * 128 + colg * 4];
        #pragma unroll
        for (int j = 0; j < 4; ++j) num[j] += bf2f(pv[j]);
    }
    float inv = 1.0f / den;
    f32x4 res = { num[0] * inv, num[1] * inv, num[2] * inv, num[3] * inv };
    *(f32x4*)&out[((size_t)b * 4096 + qb * 128 + qr) * 128 + colg * 4] = res;
}

extern "C" void kernel_launch(void* const* d_in, const int* in_sizes, int n_in,
                              void* d_out, int out_size, void* d_ws, size_t ws_size,
                              hipStream_t stream) {
    (void)in_sizes; (void)n_in; (void)out_size;
    const float* x  = (const float*)d_in[0];
    const float* Wq = (const float*)d_in[1];
    const float* Wk = (const float*)d_in[2];
    const float* Wv = (const float*)d_in[3];
    float* out = (float*)d_out;

    // Layout: [Qf Kf Vf | scratch]; scratch aliased:
    //   phase 1 (prep/qkv): xf (16 MB) + wf (0.4 MB)
    //   phase 2 (attn/merge): po (35.65 MB) + pml (0.56 MB)
    u16* Qf = (u16*)d_ws;                    // 2,097,152 u16 each
    u16* Kf = Qf + 2097152;
    u16* Vf = Kf + 2097152;
    u16* xf = Vf + 2097152;                  // 8,388,608 u16
    u16* wf = xf + 8388608;                  //   196,608 u16
    u16* po = xf;                            // alias (xf/wf dead after qkv2)
    float* pml = (float*)(po + (size_t)1088 * 128 * 128);

    const size_t fixed_b = (size_t)3 * 2097152 * 2;                   // 12,582,912
    const size_t part_b  = (size_t)1088 * 128 * (128 * 2 + 4);        // 36,208,640
    const int split = (ws_size >= fixed_b + part_b) ? 1 : 0;          // 48.8 MB

    prep_all<<<1120, 256, 0, stream>>>(x, Wq, Wk, Wv, xf, wf);
    qkv2<<<dim3(256, 3), 256, 0, stream>>>(xf, wf, Qf, Kf, Vf);
    attn8<<<split ? 1088 : 128, 256, 0, stream>>>(Qf, Kf, Vf, out, po, pml, split);
    if (split) merge6<<<1920, 256, 0, stream>>>(po, pml, out);
}

// Round 17
// 85.418 us; speedup vs baseline: 1.1843x; 1.1843x over previous
//
#include <hip/hip_runtime.h>

typedef __bf16 bf16x8 __attribute__((ext_vector_type(8)));
typedef float f32x4 __attribute__((ext_vector_type(4)));
typedef unsigned short u16;
typedef unsigned int u32;
typedef u16 u16x8 __attribute__((ext_vector_type(8)));
typedef u16 u16x4 __attribute__((ext_vector_type(4)));
typedef u32 u32x4 __attribute__((ext_vector_type(4)));

__device__ __forceinline__ u16 f2bf(float f) {
    u32 u = __builtin_bit_cast(u32, f);
    u += 0x7fffu + ((u >> 16) & 1u);   // RNE
    return (u16)(u >> 16);
}
__device__ __forceinline__ float bf2f(u16 v) {
    return __builtin_bit_cast(float, (u32)v << 16);
}
__device__ __forceinline__ u32 cvtpk(float a, float b) {   // lo=bf16(a), hi=bf16(b)
    u32 d;
    asm("v_cvt_pk_bf16_f32 %0, %1, %2" : "=v"(d) : "v"(a), "v"(b));
    return d;
}
__device__ __forceinline__ f32x4 mfma16(u16x8 a, u16x8 b, f32x4 c) {
    return __builtin_amdgcn_mfma_f32_16x16x32_bf16(
        __builtin_bit_cast(bf16x8, a), __builtin_bit_cast(bf16x8, b), c, 0, 0, 0);
}

#define GLOAD16(SRC, DST)                                                     \
    __builtin_amdgcn_global_load_lds(                                         \
        (const __attribute__((address_space(1))) unsigned int*)(SRC),         \
        (__attribute__((address_space(3))) unsigned int*)(DST), 16, 0, 0)

// chunk-XOR LDS addressing for a [16][128] u16 tile (16B chunks, XOR row into chunk)
__device__ __forceinline__ int ldsAddr(int r, int c) {       // u16 index
    return r * 128 + (((c >> 3) ^ (r & 7)) << 3) + (c & 7);
}

// ---------------------------------------------------------------------------
// Kernel 0: fused prep. Blocks [0,1024): x fp32 -> xf frag-major bf16.
// Blocks [1024,1120): W fp32 [512][128] -> Wf frag-major bf16
// (Wq pre-scaled by 1/sqrt(128)*log2(e) for log2-domain softmax).
// ---------------------------------------------------------------------------
__global__ __launch_bounds__(256) void prep_all(
    const float* __restrict__ x,
    const float* __restrict__ Wq, const float* __restrict__ Wk,
    const float* __restrict__ Wv,
    u16* __restrict__ xf, u16* __restrict__ wf)
{
    __shared__ u16 T[16 * 512];
    const int t = threadIdx.x;
    if (blockIdx.x < 1024) {
        const int rb = blockIdx.x;
        const int row = t >> 4, colb = (t & 15) * 32;
        const float* src = x + (size_t)(rb * 16 + row) * 512 + colb;
        #pragma unroll
        for (int i = 0; i < 4; ++i) {
            float4 va = *(const float4*)(src + i * 8);
            float4 vb = *(const float4*)(src + i * 8 + 4);
            u16x8 v;
            v[0] = f2bf(va.x); v[1] = f2bf(va.y); v[2] = f2bf(va.z); v[3] = f2bf(va.w);
            v[4] = f2bf(vb.x); v[5] = f2bf(vb.y); v[6] = f2bf(vb.z); v[7] = f2bf(vb.w);
            int chunk = ((colb >> 3) + i) ^ (row & 7);
            *(u16x8*)&T[row * 512 + chunk * 8] = v;
        }
        __syncthreads();
        #pragma unroll
        for (int ii = 0; ii < 4; ++ii) {
            int flatF = ii * 256 + t;
            int ds = flatF >> 6, lane = flatF & 63;
            int l16 = lane & 15, g = lane >> 4;
            int chunk = (4 * ds + g) ^ (l16 & 7);
            u16x8 v = *(const u16x8*)&T[l16 * 512 + chunk * 8];
            *(u16x8*)&xf[(((size_t)rb * 16 + ds) * 64 + lane) * 8] = v;
        }
    } else {
        int flat = (blockIdx.x - 1024) * 256 + t;      // [0, 24576)
        int widx = flat >> 13, rem = flat & 8191;
        int n = rem >> 10, ds = (rem >> 6) & 15, lane = rem & 63;
        int l16 = lane & 15, g = lane >> 4;
        const float* W = (widx == 0) ? Wq : (widx == 1 ? Wk : Wv);
        const float sc = (widx == 0) ? (0.08838834764831845f * 1.4426950408889634f) : 1.0f;
        u16x8 v;
        #pragma unroll
        for (int j = 0; j < 8; ++j)
            v[j] = f2bf(W[(size_t)(ds * 32 + 8 * g + j) * 128 + n * 16 + l16] * sc);
        *(u16x8*)&wf[(size_t)flat * 8] = v;
    }
}

// ---------------------------------------------------------------------------
// Kernel 1: QKV GEMM with LDS-staged W slices (round-13, measured good).
// Block = 4 waves x 16 rows; grid (256, 3) = 768 blocks -> 3 blocks/CU.
// ---------------------------------------------------------------------------
__global__ __launch_bounds__(256, 3) void qkv2(
    const u16* __restrict__ xf, const u16* __restrict__ wf,
    u16* __restrict__ Qf, u16* __restrict__ Kf, u16* __restrict__ Vf)
{
    __shared__ u16 Wbuf[2][4096];    // [buf][n*64+lane -> 8 u16]  (8 KB each)
    __shared__ u16 T4[4][16 * 128];
    const int tid = threadIdx.x, lane = tid & 63, wid = tid >> 6;
    const int g = lane >> 4, l16 = lane & 15;
    const int widx = blockIdx.y;
    const int rbg = blockIdx.x * 4 + wid;        // 16-row block [0,1024)
    const u16* WfB = wf + (size_t)widx * 65536;
    u16* T = T4[wid];

    GLOAD16(WfB + (size_t)((wid * 16 + 0) * 64 + lane) * 8,
            Wbuf[0] + (wid * 64 + lane) * 8);
    GLOAD16(WfB + (size_t)(((wid + 4) * 16 + 0) * 64 + lane) * 8,
            Wbuf[0] + ((wid + 4) * 64 + lane) * 8);

    const f32x4 fz = {0.f, 0.f, 0.f, 0.f};
    f32x4 acc[8];
    #pragma unroll
    for (int n = 0; n < 8; ++n) acc[n] = fz;

    u16x8 a_cur = *(const u16x8*)&xf[(((size_t)rbg * 16 + 0) * 64 + lane) * 8];
    __syncthreads();                              // slice 0 staged

    #pragma unroll 1
    for (int ds = 0; ds < 16; ++ds) {
        u16x8 a_next;
        if (ds + 1 < 16) {
            const int nds = ds + 1, bb = nds & 1;
            GLOAD16(WfB + (size_t)((wid * 16 + nds) * 64 + lane) * 8,
                    Wbuf[bb] + (wid * 64 + lane) * 8);
            GLOAD16(WfB + (size_t)(((wid + 4) * 16 + nds) * 64 + lane) * 8,
                    Wbuf[bb] + ((wid + 4) * 64 + lane) * 8);
            a_next = *(const u16x8*)&xf[(((size_t)rbg * 16 + nds) * 64 + lane) * 8];
        }
        const u16* Wl = Wbuf[ds & 1];
        #pragma unroll
        for (int n = 0; n < 8; ++n) {
            u16x8 b = *(const u16x8*)&Wl[(n * 64 + lane) * 8];
            acc[n] = mfma16(a_cur, b, acc[n]);
        }
        __syncthreads();
        if (ds + 1 < 16) a_cur = a_next;
    }

    #pragma unroll
    for (int n = 0; n < 8; ++n) {
        #pragma unroll
        for (int r = 0; r < 4; ++r)
            T[ldsAddr(4 * g + r, n * 16 + l16)] = f2bf(acc[n][r]);
    }
    if (widx < 2) {
        u16* dst = (widx == 0) ? Qf : Kf;
        #pragma unroll
        for (int ds = 0; ds < 4; ++ds) {
            int chunk = (4 * ds + g) ^ (l16 & 7);
            u16x8 v = *(const u16x8*)&T[l16 * 128 + chunk * 8];
            *(u16x8*)&dst[(((size_t)rbg * 4 + ds) * 64 + lane) * 8] = v;
        }
    } else {
        const int kb = rbg >> 2, ksel = (rbg >> 1) & 1, g0 = (rbg & 1) * 2;
        #pragma unroll
        for (int s = 0; s < 4; ++s) {
            int flat = s * 64 + lane;
            int e = flat >> 5, gg = (flat >> 4) & 1, l16p = flat & 15;
            u16x8 v;
            #pragma unroll
            for (int j = 0; j < 8; ++j)
                v[j] = T[ldsAddr(8 * gg + j, e * 16 + l16p)];
            *(u16x8*)&Vf[((((size_t)kb * 2 + ksel) * 8 + e) * 64
                          + (g0 + gg) * 16 + l16p) * 8] = v;
        }
    }
}

// ---------------------------------------------------------------------------
// Kernel 2: causal flash attention — K-only 3-deep LDS ring + counted vmcnt,
// V fragments direct from global (L2-served; safe at 2 blocks/CU).
// ring[4][8192] u16 = 64 KB exactly -> hard 2 blocks/CU (the proven L2-safe
// point). K prefetch distance 2; vmcnt(4) at raw s_barrier keeps the fresh
// 4 K-gloads in flight (r16 measured +25% per-wave from this pipeline).
// Unnormalized log2 softmax, setprio around MFMA (r12-proven).
// ---------------------------------------------------------------------------
__global__ __launch_bounds__(256, 2) void attn9(
    const u16* __restrict__ Qf, const u16* __restrict__ Kf,
    const u16* __restrict__ Vf, float* __restrict__ out,
    u16* __restrict__ po, float* __restrict__ pml, int split)
{
    __shared__ u16 ring[4][8192];   // 4 x 16 KB = 64 KB; slots 0..2 used
    const int tid = threadIdx.x, lane = tid & 63, wid = tid >> 6;
    const int g = lane >> 4, l16 = lane & 15;

    int b, qb, c, u;
    if (split) {
        const int xcd = blockIdx.x & 7;        // XCD pair {2b,2b+1} -> batch b
        b = xcd >> 1;
        int jb = 271 - ((xcd & 1) * 136 + (blockIdx.x >> 3));   // longest-first
        u = 0;
        while ((u + 1) * (u + 2) <= jb) ++u;   // u(u+1) <= jb < (u+1)(u+2)
        int r = jb - u * (u + 1);
        int hi = (r >= u + 1) ? 1 : 0;
        qb = 2 * u + hi;
        c = r - hi * (u + 1);
    } else {
        b = blockIdx.x & 3;
        qb = blockIdx.x >> 2;
        c = 0; u = 0;
    }
    const int q0 = qb * 128 + wid * 32;        // wave's first q row
    const int k_lo = c * 256;
    const int k_hi = min(k_lo + (split ? 256 : 4096), qb * 128 + 128);
    const int nch = u + 1;
    const int wklen = q0 + 32;                 // wave needs tiles with k0 < wklen
    const int nt = (k_hi - k_lo) >> 6;         // 64-key tiles (>= 2)

    // prologue: Q frags + stage K tiles 0,1 (each wave stages its 4KB quarter)
    const int rbq = b * 256 + qb * 8 + wid * 2;
    u16x8 qf0[4], qf1[4];
    #pragma unroll
    for (int ds = 0; ds < 4; ++ds) {
        qf0[ds] = *(const u16x8*)&Qf[(((size_t)rbq * 4 + ds) * 64 + lane) * 8];
        qf1[ds] = *(const u16x8*)&Qf[(((size_t)(rbq + 1) * 4 + ds) * 64 + lane) * 8];
    }
    {
        const u16* s0 = Kf + (size_t)(b * 256 + (k_lo >> 4)) * 2048 + wid * 2048;
        #pragma unroll
        for (int j = 0; j < 4; ++j)
            GLOAD16(s0 + j * 512 + lane * 8, &ring[0][wid * 2048 + j * 512]);
        const u16* s1 = Kf + (size_t)(b * 256 + ((k_lo + 64) >> 4)) * 2048 + wid * 2048;
        #pragma unroll
        for (int j = 0; j < 4; ++j)
            GLOAD16(s1 + j * 512 + lane * 8, &ring[1][wid * 2048 + j * 512]);
    }

    const f32x4 fz = {0.f, 0.f, 0.f, 0.f};
    f32x4 o0[8], o1[8];
    #pragma unroll
    for (int e = 0; e < 8; ++e) { o0[e] = fz; o1[e] = fz; }
    float l0 = 0.f, l1 = 0.f;                  // per-lane partial denominators

    const int srcA = l16 + ((g & 1) << 5);
    const int srcB = srcA + 16;
    const bool hiSel = (g >= 2);

    __syncthreads();                            // full drain once (tiles 0,1)

    int bi = 0;
    #pragma unroll 1
    for (int it = 0; it < nt; ++it) {
        const int k0 = k_lo + (it << 6);
        const bool pf = (it + 2 < nt);
        if (k0 < wklen) {
            const u16* Kl = ring[bi];
            const size_t vbase = (size_t)(b * 64 + (k0 >> 6)) * 8192;
            // ---- S^T = K * Q^T for both q-halves (K frags shared) ----
            f32x4 st0[4], st1[4];
            __builtin_amdgcn_s_setprio(1);
            #pragma unroll
            for (int kt = 0; kt < 4; ++kt) {
                st0[kt] = fz; st1[kt] = fz;
                #pragma unroll
                for (int ds = 0; ds < 4; ++ds) {
                    u16x8 kf = *(const u16x8*)&Kl[(kt * 4 + ds) * 512 + lane * 8];
                    st0[kt] = mfma16(kf, qf0[ds], st0[kt]);
                    st1[kt] = mfma16(kf, qf1[ds], st1[kt]);
                }
            }
            __builtin_amdgcn_s_setprio(0);
            // ---- causal mask (diagonal tiles only), per half ----
            if (k0 + 63 > q0) {
                int qg = q0 + l16;
                #pragma unroll
                for (int kt = 0; kt < 4; ++kt)
                    #pragma unroll
                    for (int r = 0; r < 4; ++r)
                        if (k0 + kt * 16 + g * 4 + r > qg) st0[kt][r] = -1e30f;
            }
            if (k0 + 63 > q0 + 16) {
                int qg = q0 + 16 + l16;
                #pragma unroll
                for (int kt = 0; kt < 4; ++kt)
                    #pragma unroll
                    for (int r = 0; r < 4; ++r)
                        if (k0 + kt * 16 + g * 4 + r > qg) st1[kt][r] = -1e30f;
            }
            // ---- unnormalized softmax: p = exp2(st), per-lane l accumulate ----
            u32 pk0[4][2], pk1[4][2];
            #pragma unroll
            for (int kt = 0; kt < 4; ++kt) {
                float p0 = exp2f(st0[kt][0]), p1 = exp2f(st0[kt][1]);
                float p2 = exp2f(st0[kt][2]), p3 = exp2f(st0[kt][3]);
                l0 += (p0 + p1) + (p2 + p3);
                pk0[kt][0] = cvtpk(p0, p1);
                pk0[kt][1] = cvtpk(p2, p3);
                float q0v = exp2f(st1[kt][0]), q1v = exp2f(st1[kt][1]);
                float q2v = exp2f(st1[kt][2]), q3v = exp2f(st1[kt][3]);
                l1 += (q0v + q1v) + (q2v + q3v);
                pk1[kt][0] = cvtpk(q0v, q1v);
                pk1[kt][1] = cvtpk(q2v, q3v);
            }
            // ---- P redistribute (in-register) + O^T += V^T * P^T (V global) ----
            #pragma unroll
            for (int ksel = 0; ksel < 2; ++ksel) {
                u32 a0 = __shfl((int)pk0[2 * ksel][0], srcA), b0 = __shfl((int)pk0[2 * ksel + 1][0], srcA);
                u32 a1 = __shfl((int)pk0[2 * ksel][1], srcA), b1 = __shfl((int)pk0[2 * ksel + 1][1], srcA);
                u32 a2 = __shfl((int)pk0[2 * ksel][0], srcB), b2 = __shfl((int)pk0[2 * ksel + 1][0], srcB);
                u32 a3 = __shfl((int)pk0[2 * ksel][1], srcB), b3 = __shfl((int)pk0[2 * ksel + 1][1], srcB);
                u32x4 d0 = { hiSel ? b0 : a0, hiSel ? b1 : a1, hiSel ? b2 : a2, hiSel ? b3 : a3 };
                u16x8 pf0 = __builtin_bit_cast(u16x8, d0);
                u32 c0 = __shfl((int)pk1[2 * ksel][0], srcA), e0 = __shfl((int)pk1[2 * ksel + 1][0], srcA);
                u32 c1 = __shfl((int)pk1[2 * ksel][1], srcA), e1 = __shfl((int)pk1[2 * ksel + 1][1], srcA);
                u32 c2 = __shfl((int)pk1[2 * ksel][0], srcB), e2 = __shfl((int)pk1[2 * ksel + 1][0], srcB);
                u32 c3 = __shfl((int)pk1[2 * ksel][1], srcB), e3 = __shfl((int)pk1[2 * ksel + 1][1], srcB);
                u32x4 d1 = { hiSel ? e0 : c0, hiSel ? e1 : c1, hiSel ? e2 : c2, hiSel ? e3 : c3 };
                u16x8 pf1 = __builtin_bit_cast(u16x8, d1);
                __builtin_amdgcn_s_setprio(1);
                #pragma unroll
                for (int e = 0; e < 8; ++e) {
                    u16x8 vf = *(const u16x8*)&Vf[vbase + (ksel * 8 + e) * 512 + lane * 8];
                    o0[e] = mfma16(vf, pf0, o0[e]);
                    o1[e] = mfma16(vf, pf1, o1[e]);
                }
                __builtin_amdgcn_s_setprio(0);
            }
        }
        // ---- pinned prefetch cluster + counted-vmcnt barrier (T4) ----
        __builtin_amdgcn_sched_barrier(0);
        if (pf) {
            const int kn = k0 + 128;
            int pi = bi + 2; if (pi >= 3) pi -= 3;
            const u16* src = Kf + (size_t)(b * 256 + (kn >> 4)) * 2048 + wid * 2048;
            #pragma unroll
            for (int j = 0; j < 4; ++j)
                GLOAD16(src + j * 512 + lane * 8, &ring[pi][wid * 2048 + j * 512]);
            asm volatile("s_waitcnt vmcnt(4) lgkmcnt(0)" ::: "memory");
        } else {
            asm volatile("s_waitcnt vmcnt(0) lgkmcnt(0)" ::: "memory");
        }
        __builtin_amdgcn_s_barrier();
        __builtin_amdgcn_sched_barrier(0);
        bi = (bi == 2) ? 0 : bi + 1;
    }

    // reduce per-lane denominators across the 4 k-groups (once per block)
    l0 += __shfl_xor(l0, 16); l0 += __shfl_xor(l0, 32);
    l1 += __shfl_xor(l1, 16); l1 += __shfl_xor(l1, 32);

    if (nch == 1) {
        float inv0 = 1.0f / l0, inv1 = 1.0f / l1;
        float* op0 = out + ((size_t)b * 4096 + q0 + l16) * 128;
        float* op1 = out + ((size_t)b * 4096 + q0 + 16 + l16) * 128;
        #pragma unroll
        for (int e = 0; e < 8; ++e) {
            f32x4 v0 = o0[e], v1 = o1[e];
            #pragma unroll
            for (int r = 0; r < 4; ++r) { v0[r] *= inv0; v1[r] *= inv1; }
            *(f32x4*)&op0[e * 16 + g * 4] = v0;
            *(f32x4*)&op1[e * 16 + g * 4] = v1;
        }
    } else {
        const int slot = b * 272 + u * (u + 1) + (qb & 1) * (u + 1) + c;
        u16* pp0 = po + ((size_t)slot * 128 + wid * 32 + l16) * 128;
        u16* pp1 = pp0 + 16 * 128;
        #pragma unroll
        for (int e = 0; e < 8; ++e) {
            u16x4 v0, v1;
            #pragma unroll
            for (int r = 0; r < 4; ++r) { v0[r] = f2bf(o0[e][r]); v1[r] = f2bf(o1[e][r]); }
            *(u16x4*)&pp0[e * 16 + g * 4] = v0;
            *(u16x4*)&pp1[e * 16 + g * 4] = v1;
        }
        if (g == 0) {
            pml[(size_t)slot * 128 + wid * 32 + l16] = l0;
            pml[(size_t)slot * 128 + wid * 32 + 16 + l16] = l1;
        }
    }
}

// ---------------------------------------------------------------------------
// Kernel 3: merge split-K partials (qb >= 2). Plain sums (no max logic).
// ---------------------------------------------------------------------------
__global__ __launch_bounds__(256) void merge6(
    const u16* __restrict__ po, const float* __restrict__ pml,
    float* __restrict__ out)
{
    int gid = blockIdx.x * 256 + threadIdx.x;   // 491,520 total
    int colg = gid & 31;
    int rowid = gid >> 5;                        // [0, 15360)
    int b = rowid / 3840;
    int rr = rowid - b * 3840;
    int qb = (rr >> 7) + 2;
    int qr = rr & 127;
    int u = qb >> 1;
    int nch = u + 1;
    int slot0 = b * 272 + u * (u + 1) + (qb & 1) * (u + 1);

    float den = 0.f;
    f32x4 num = {0.f, 0.f, 0.f, 0.f};
    #pragma unroll 1
    for (int cc = 0; cc < nch; ++cc) {
        den += pml[(size_t)(slot0 + cc) * 128 + qr];
        u16x4 pv = *(const u16x4*)&po[((size_t)(slot0 + cc) * 128 + qr) * 128 + colg * 4];
        #pragma unroll
        for (int j = 0; j < 4; ++j) num[j] += bf2f(pv[j]);
    }
    float inv = 1.0f / den;
    f32x4 res = { num[0] * inv, num[1] * inv, num[2] * inv, num[3] * inv };
    *(f32x4*)&out[((size_t)b * 4096 + qb * 128 + qr) * 128 + colg * 4] = res;
}

extern "C" void kernel_launch(void* const* d_in, const int* in_sizes, int n_in,
                              void* d_out, int out_size, void* d_ws, size_t ws_size,
                              hipStream_t stream) {
    (void)in_sizes; (void)n_in; (void)out_size;
    const float* x  = (const float*)d_in[0];
    const float* Wq = (const float*)d_in[1];
    const float* Wk = (const float*)d_in[2];
    const float* Wv = (const float*)d_in[3];
    float* out = (float*)d_out;

    // Layout: [Qf Kf Vf | scratch]; scratch aliased:
    //   phase 1 (prep/qkv): xf (16 MB) + wf (0.4 MB)
    //   phase 2 (attn/merge): po (35.65 MB) + pml (0.56 MB)
    u16* Qf = (u16*)d_ws;                    // 2,097,152 u16 each
    u16* Kf = Qf + 2097152;
    u16* Vf = Kf + 2097152;
    u16* xf = Vf + 2097152;                  // 8,388,608 u16
    u16* wf = xf + 8388608;                  //   196,608 u16
    u16* po = xf;                            // alias (xf/wf dead after qkv2)
    float* pml = (float*)(po + (size_t)1088 * 128 * 128);

    const size_t fixed_b = (size_t)3 * 2097152 * 2;                   // 12,582,912
    const size_t part_b  = (size_t)1088 * 128 * (128 * 2 + 4);        // 36,208,640
    const int split = (ws_size >= fixed_b + part_b) ? 1 : 0;          // 48.8 MB

    prep_all<<<1120, 256, 0, stream>>>(x, Wq, Wk, Wv, xf, wf);
    qkv2<<<dim3(256, 3), 256, 0, stream>>>(xf, wf, Qf, Kf, Vf);
    attn9<<<split ? 1088 : 128, 256, 0, stream>>>(Qf, Kf, Vf, out, po, pml, split);
    if (split) merge6<<<1920, 256, 0, stream>>>(po, pml, out);
}

// Round 18
// 82.796 us; speedup vs baseline: 1.2218x; 1.0317x over previous
//
#include <hip/hip_runtime.h>

typedef __bf16 bf16x8 __attribute__((ext_vector_type(8)));
typedef float f32x4 __attribute__((ext_vector_type(4)));
typedef unsigned short u16;
typedef unsigned int u32;
typedef u16 u16x8 __attribute__((ext_vector_type(8)));
typedef u16 u16x4 __attribute__((ext_vector_type(4)));
typedef u32 u32x4 __attribute__((ext_vector_type(4)));

__device__ __forceinline__ u16 f2bf(float f) {
    u32 u = __builtin_bit_cast(u32, f);
    u += 0x7fffu + ((u >> 16) & 1u);   // RNE
    return (u16)(u >> 16);
}
__device__ __forceinline__ float bf2f(u16 v) {
    return __builtin_bit_cast(float, (u32)v << 16);
}
__device__ __forceinline__ u32 cvtpk(float a, float b) {   // lo=bf16(a), hi=bf16(b)
    u32 d;
    asm("v_cvt_pk_bf16_f32 %0, %1, %2" : "=v"(d) : "v"(a), "v"(b));
    return d;
}
__device__ __forceinline__ f32x4 mfma16(u16x8 a, u16x8 b, f32x4 c) {
    return __builtin_amdgcn_mfma_f32_16x16x32_bf16(
        __builtin_bit_cast(bf16x8, a), __builtin_bit_cast(bf16x8, b), c, 0, 0, 0);
}

#define GLOAD16(SRC, DST)                                                     \
    __builtin_amdgcn_global_load_lds(                                         \
        (const __attribute__((address_space(1))) unsigned int*)(SRC),         \
        (__attribute__((address_space(3))) unsigned int*)(DST), 16, 0, 0)

// chunk-XOR LDS addressing for a [16][128] u16 tile (16B chunks, XOR row into chunk)
__device__ __forceinline__ int ldsAddr(int r, int c) {       // u16 index
    return r * 128 + (((c >> 3) ^ (r & 7)) << 3) + (c & 7);
}

// ---------------------------------------------------------------------------
// Kernel 0: fused prep. Blocks [0,1024): x fp32 -> xf frag-major bf16.
// Blocks [1024,1120): W fp32 [512][128] -> Wf frag-major bf16
// (Wq pre-scaled by 1/sqrt(128)*log2(e) for log2-domain softmax).
// ---------------------------------------------------------------------------
__global__ __launch_bounds__(256) void prep_all(
    const float* __restrict__ x,
    const float* __restrict__ Wq, const float* __restrict__ Wk,
    const float* __restrict__ Wv,
    u16* __restrict__ xf, u16* __restrict__ wf)
{
    __shared__ u16 T[16 * 512];
    const int t = threadIdx.x;
    if (blockIdx.x < 1024) {
        const int rb = blockIdx.x;
        const int row = t >> 4, colb = (t & 15) * 32;
        const float* src = x + (size_t)(rb * 16 + row) * 512 + colb;
        #pragma unroll
        for (int i = 0; i < 4; ++i) {
            float4 va = *(const float4*)(src + i * 8);
            float4 vb = *(const float4*)(src + i * 8 + 4);
            u16x8 v;
            v[0] = f2bf(va.x); v[1] = f2bf(va.y); v[2] = f2bf(va.z); v[3] = f2bf(va.w);
            v[4] = f2bf(vb.x); v[5] = f2bf(vb.y); v[6] = f2bf(vb.z); v[7] = f2bf(vb.w);
            int chunk = ((colb >> 3) + i) ^ (row & 7);
            *(u16x8*)&T[row * 512 + chunk * 8] = v;
        }
        __syncthreads();
        #pragma unroll
        for (int ii = 0; ii < 4; ++ii) {
            int flatF = ii * 256 + t;
            int ds = flatF >> 6, lane = flatF & 63;
            int l16 = lane & 15, g = lane >> 4;
            int chunk = (4 * ds + g) ^ (l16 & 7);
            u16x8 v = *(const u16x8*)&T[l16 * 512 + chunk * 8];
            *(u16x8*)&xf[(((size_t)rb * 16 + ds) * 64 + lane) * 8] = v;
        }
    } else {
        int flat = (blockIdx.x - 1024) * 256 + t;      // [0, 24576)
        int widx = flat >> 13, rem = flat & 8191;
        int n = rem >> 10, ds = (rem >> 6) & 15, lane = rem & 63;
        int l16 = lane & 15, g = lane >> 4;
        const float* W = (widx == 0) ? Wq : (widx == 1 ? Wk : Wv);
        const float sc = (widx == 0) ? (0.08838834764831845f * 1.4426950408889634f) : 1.0f;
        u16x8 v;
        #pragma unroll
        for (int j = 0; j < 8; ++j)
            v[j] = f2bf(W[(size_t)(ds * 32 + 8 * g + j) * 128 + n * 16 + l16] * sc);
        *(u16x8*)&wf[(size_t)flat * 8] = v;
    }
}

// ---------------------------------------------------------------------------
// Kernel 1: QKV GEMM with LDS-staged W slices (round-13, measured good).
// Block = 4 waves x 16 rows; grid (256, 3) = 768 blocks -> 3 blocks/CU.
// ---------------------------------------------------------------------------
__global__ __launch_bounds__(256, 3) void qkv2(
    const u16* __restrict__ xf, const u16* __restrict__ wf,
    u16* __restrict__ Qf, u16* __restrict__ Kf, u16* __restrict__ Vf)
{
    __shared__ u16 Wbuf[2][4096];    // [buf][n*64+lane -> 8 u16]  (8 KB each)
    __shared__ u16 T4[4][16 * 128];
    const int tid = threadIdx.x, lane = tid & 63, wid = tid >> 6;
    const int g = lane >> 4, l16 = lane & 15;
    const int widx = blockIdx.y;
    const int rbg = blockIdx.x * 4 + wid;        // 16-row block [0,1024)
    const u16* WfB = wf + (size_t)widx * 65536;
    u16* T = T4[wid];

    GLOAD16(WfB + (size_t)((wid * 16 + 0) * 64 + lane) * 8,
            Wbuf[0] + (wid * 64 + lane) * 8);
    GLOAD16(WfB + (size_t)(((wid + 4) * 16 + 0) * 64 + lane) * 8,
            Wbuf[0] + ((wid + 4) * 64 + lane) * 8);

    const f32x4 fz = {0.f, 0.f, 0.f, 0.f};
    f32x4 acc[8];
    #pragma unroll
    for (int n = 0; n < 8; ++n) acc[n] = fz;

    u16x8 a_cur = *(const u16x8*)&xf[(((size_t)rbg * 16 + 0) * 64 + lane) * 8];
    __syncthreads();                              // slice 0 staged

    #pragma unroll 1
    for (int ds = 0; ds < 16; ++ds) {
        u16x8 a_next;
        if (ds + 1 < 16) {
            const int nds = ds + 1, bb = nds & 1;
            GLOAD16(WfB + (size_t)((wid * 16 + nds) * 64 + lane) * 8,
                    Wbuf[bb] + (wid * 64 + lane) * 8);
            GLOAD16(WfB + (size_t)(((wid + 4) * 16 + nds) * 64 + lane) * 8,
                    Wbuf[bb] + ((wid + 4) * 64 + lane) * 8);
            a_next = *(const u16x8*)&xf[(((size_t)rbg * 16 + nds) * 64 + lane) * 8];
        }
        const u16* Wl = Wbuf[ds & 1];
        #pragma unroll
        for (int n = 0; n < 8; ++n) {
            u16x8 b = *(const u16x8*)&Wl[(n * 64 + lane) * 8];
            acc[n] = mfma16(a_cur, b, acc[n]);
        }
        __syncthreads();
        if (ds + 1 < 16) a_cur = a_next;
    }

    #pragma unroll
    for (int n = 0; n < 8; ++n) {
        #pragma unroll
        for (int r = 0; r < 4; ++r)
            T[ldsAddr(4 * g + r, n * 16 + l16)] = f2bf(acc[n][r]);
    }
    if (widx < 2) {
        u16* dst = (widx == 0) ? Qf : Kf;
        #pragma unroll
        for (int ds = 0; ds < 4; ++ds) {
            int chunk = (4 * ds + g) ^ (l16 & 7);
            u16x8 v = *(const u16x8*)&T[l16 * 128 + chunk * 8];
            *(u16x8*)&dst[(((size_t)rbg * 4 + ds) * 64 + lane) * 8] = v;
        }
    } else {
        const int kb = rbg >> 2, ksel = (rbg >> 1) & 1, g0 = (rbg & 1) * 2;
        #pragma unroll
        for (int s = 0; s < 4; ++s) {
            int flat = s * 64 + lane;
            int e = flat >> 5, gg = (flat >> 4) & 1, l16p = flat & 15;
            u16x8 v;
            #pragma unroll
            for (int j = 0; j < 8; ++j)
                v[j] = T[ldsAddr(8 * gg + j, e * 16 + l16p)];
            *(u16x8*)&Vf[((((size_t)kb * 2 + ksel) * 8 + e) * 64
                          + (g0 + gg) * 16 + l16p) * 8] = v;
        }
    }
}

// ---------------------------------------------------------------------------
// Kernel 2: causal flash attention — 32-key tiles, K+V in a 4-slot LDS ring
// (16KB/slot, 64KB total -> proven 2 blocks/CU), prefetch distance 2 with
// counted vmcnt(4) at a raw s_barrier (T4; r16 measured +25% per-wave).
// Inner 32-key body = r14's (correctness-proven); unnormalized log2 softmax.
// ---------------------------------------------------------------------------
__global__ __launch_bounds__(256, 2) void attn10(
    const u16* __restrict__ Qf, const u16* __restrict__ Kf,
    const u16* __restrict__ Vf, float* __restrict__ out,
    u16* __restrict__ po, float* __restrict__ pml, int split)
{
    __shared__ u16 ring[4][8192];   // slot: [ K 8KB | V 8KB ]; 4 slots = 64 KB
    const int tid = threadIdx.x, lane = tid & 63, wid = tid >> 6;
    const int g = lane >> 4, l16 = lane & 15;

    int b, qb, c, u;
    if (split) {
        const int xcd = blockIdx.x & 7;        // XCD pair {2b,2b+1} -> batch b
        b = xcd >> 1;
        int jb = 271 - ((xcd & 1) * 136 + (blockIdx.x >> 3));   // longest-first
        u = 0;
        while ((u + 1) * (u + 2) <= jb) ++u;   // u(u+1) <= jb < (u+1)(u+2)
        int r = jb - u * (u + 1);
        int hi = (r >= u + 1) ? 1 : 0;
        qb = 2 * u + hi;
        c = r - hi * (u + 1);
    } else {
        b = blockIdx.x & 3;
        qb = blockIdx.x >> 2;
        c = 0; u = 0;
    }
    const int q0 = qb * 128 + wid * 32;        // wave's first q row
    const int k_lo = c * 256;
    const int k_hi = min(k_lo + (split ? 256 : 4096), qb * 128 + 128);
    const int nch = u + 1;
    const int wklen = q0 + 32;                 // wave needs tiles with k0 < wklen
    const int nt = (k_hi - k_lo) >> 5;         // 32-key tiles (>= 4)

    // per-wave staging source for a 32-key tile at key offset kk:
    //   wid 0,1 -> K halves; wid 2,3 -> V halves (each 4 gloads of 1KB)
    // prologue: Q frags + stage tiles 0,1 into slots 0,1
    const int rbq = b * 256 + qb * 8 + wid * 2;
    u16x8 qf0[4], qf1[4];
    #pragma unroll
    for (int ds = 0; ds < 4; ++ds) {
        qf0[ds] = *(const u16x8*)&Qf[(((size_t)rbq * 4 + ds) * 64 + lane) * 8];
        qf1[ds] = *(const u16x8*)&Qf[(((size_t)(rbq + 1) * 4 + ds) * 64 + lane) * 8];
    }
    #pragma unroll
    for (int s = 0; s < 2; ++s) {
        const int kk = k_lo + s * 32;
        const u16* src;
        u16* dst;
        if (wid < 2) {
            src = Kf + (size_t)(b * 256 + (kk >> 4)) * 2048 + wid * 2048;
            dst = &ring[s][wid * 2048];
        } else {
            src = Vf + (size_t)(b * 64 + (kk >> 6)) * 8192
                     + ((kk >> 5) & 1) * 4096 + (wid - 2) * 2048;
            dst = &ring[s][4096 + (wid - 2) * 2048];
        }
        #pragma unroll
        for (int j = 0; j < 4; ++j)
            GLOAD16(src + j * 512 + lane * 8, dst + j * 512);
    }

    const f32x4 fz = {0.f, 0.f, 0.f, 0.f};
    f32x4 o0[8], o1[8];
    #pragma unroll
    for (int e = 0; e < 8; ++e) { o0[e] = fz; o1[e] = fz; }
    float l0 = 0.f, l1 = 0.f;

    const int srcA = l16 + ((g & 1) << 5);
    const int srcB = srcA + 16;
    const bool hiSel = (g >= 2);

    __syncthreads();                            // tiles 0,1 staged

    int bi = 0;
    #pragma unroll 1
    for (int it = 0; it < nt; ++it) {
        const int k0 = k_lo + (it << 5);
        const bool pf = (it + 2 < nt);
        if (k0 < wklen) {
            const u16* Kl = &ring[bi][0];
            const u16* Vl = &ring[bi][4096];
            // ---- S^T = K * Q^T (2 kt sub-tiles) ----
            f32x4 st0[2], st1[2];
            __builtin_amdgcn_s_setprio(1);
            #pragma unroll
            for (int kt = 0; kt < 2; ++kt) {
                st0[kt] = fz; st1[kt] = fz;
                #pragma unroll
                for (int ds = 0; ds < 4; ++ds) {
                    u16x8 kf = *(const u16x8*)&Kl[(kt * 4 + ds) * 512 + lane * 8];
                    st0[kt] = mfma16(kf, qf0[ds], st0[kt]);
                    st1[kt] = mfma16(kf, qf1[ds], st1[kt]);
                }
            }
            __builtin_amdgcn_s_setprio(0);
            // ---- causal mask (diagonal tiles only), per half ----
            if (k0 + 31 > q0) {
                int qg = q0 + l16;
                #pragma unroll
                for (int kt = 0; kt < 2; ++kt)
                    #pragma unroll
                    for (int r = 0; r < 4; ++r)
                        if (k0 + kt * 16 + g * 4 + r > qg) st0[kt][r] = -1e30f;
            }
            if (k0 + 31 > q0 + 16) {
                int qg = q0 + 16 + l16;
                #pragma unroll
                for (int kt = 0; kt < 2; ++kt)
                    #pragma unroll
                    for (int r = 0; r < 4; ++r)
                        if (k0 + kt * 16 + g * 4 + r > qg) st1[kt][r] = -1e30f;
            }
            // ---- unnormalized softmax: p = exp2(st) ----
            u32 pk0[2][2], pk1[2][2];
            #pragma unroll
            for (int kt = 0; kt < 2; ++kt) {
                float p0 = exp2f(st0[kt][0]), p1 = exp2f(st0[kt][1]);
                float p2 = exp2f(st0[kt][2]), p3 = exp2f(st0[kt][3]);
                l0 += (p0 + p1) + (p2 + p3);
                pk0[kt][0] = cvtpk(p0, p1);
                pk0[kt][1] = cvtpk(p2, p3);
                float q0v = exp2f(st1[kt][0]), q1v = exp2f(st1[kt][1]);
                float q2v = exp2f(st1[kt][2]), q3v = exp2f(st1[kt][3]);
                l1 += (q0v + q1v) + (q2v + q3v);
                pk1[kt][0] = cvtpk(q0v, q1v);
                pk1[kt][1] = cvtpk(q2v, q3v);
            }
            // ---- P redistribute (in-register) + O^T += V^T * P^T ----
            {
                u32 a0 = __shfl((int)pk0[0][0], srcA), b0 = __shfl((int)pk0[1][0], srcA);
                u32 a1 = __shfl((int)pk0[0][1], srcA), b1 = __shfl((int)pk0[1][1], srcA);
                u32 a2 = __shfl((int)pk0[0][0], srcB), b2 = __shfl((int)pk0[1][0], srcB);
                u32 a3 = __shfl((int)pk0[0][1], srcB), b3 = __shfl((int)pk0[1][1], srcB);
                u32x4 d0 = { hiSel ? b0 : a0, hiSel ? b1 : a1, hiSel ? b2 : a2, hiSel ? b3 : a3 };
                u16x8 pf0 = __builtin_bit_cast(u16x8, d0);
                u32 c0 = __shfl((int)pk1[0][0], srcA), e0 = __shfl((int)pk1[1][0], srcA);
                u32 c1 = __shfl((int)pk1[0][1], srcA), e1 = __shfl((int)pk1[1][1], srcA);
                u32 c2 = __shfl((int)pk1[0][0], srcB), e2 = __shfl((int)pk1[1][0], srcB);
                u32 c3 = __shfl((int)pk1[0][1], srcB), e3 = __shfl((int)pk1[1][1], srcB);
                u32x4 d1 = { hiSel ? e0 : c0, hiSel ? e1 : c1, hiSel ? e2 : c2, hiSel ? e3 : c3 };
                u16x8 pf1 = __builtin_bit_cast(u16x8, d1);
                __builtin_amdgcn_s_setprio(1);
                #pragma unroll
                for (int e = 0; e < 8; ++e) {
                    u16x8 vf = *(const u16x8*)&Vl[e * 512 + lane * 8];
                    o0[e] = mfma16(vf, pf0, o0[e]);
                    o1[e] = mfma16(vf, pf1, o1[e]);
                }
                __builtin_amdgcn_s_setprio(0);
            }
        }
        // ---- pinned prefetch cluster + counted-vmcnt barrier (T4) ----
        __builtin_amdgcn_sched_barrier(0);
        if (pf) {
            const int kn = k0 + 64;
            const int pi = (bi + 2) & 3;
            const u16* src;
            u16* dst;
            if (wid < 2) {
                src = Kf + (size_t)(b * 256 + (kn >> 4)) * 2048 + wid * 2048;
                dst = &ring[pi][wid * 2048];
            } else {
                src = Vf + (size_t)(b * 64 + (kn >> 6)) * 8192
                         + ((kn >> 5) & 1) * 4096 + (wid - 2) * 2048;
                dst = &ring[pi][4096 + (wid - 2) * 2048];
            }
            #pragma unroll
            for (int j = 0; j < 4; ++j)
                GLOAD16(src + j * 512 + lane * 8, dst + j * 512);
            asm volatile("s_waitcnt vmcnt(4) lgkmcnt(0)" ::: "memory");
        } else {
            asm volatile("s_waitcnt vmcnt(0) lgkmcnt(0)" ::: "memory");
        }
        __builtin_amdgcn_s_barrier();
        __builtin_amdgcn_sched_barrier(0);
        bi = (bi + 1) & 3;
    }

    // reduce per-lane denominators (once per block)
    l0 += __shfl_xor(l0, 16); l0 += __shfl_xor(l0, 32);
    l1 += __shfl_xor(l1, 16); l1 += __shfl_xor(l1, 32);

    if (nch == 1) {
        float inv0 = 1.0f / l0, inv1 = 1.0f / l1;
        float* op0 = out + ((size_t)b * 4096 + q0 + l16) * 128;
        float* op1 = out + ((size_t)b * 4096 + q0 + 16 + l16) * 128;
        #pragma unroll
        for (int e = 0; e < 8; ++e) {
            f32x4 v0 = o0[e], v1 = o1[e];
            #pragma unroll
            for (int r = 0; r < 4; ++r) { v0[r] *= inv0; v1[r] *= inv1; }
            *(f32x4*)&op0[e * 16 + g * 4] = v0;
            *(f32x4*)&op1[e * 16 + g * 4] = v1;
        }
    } else {
        const int slot = b * 272 + u * (u + 1) + (qb & 1) * (u + 1) + c;
        u16* pp0 = po + ((size_t)slot * 128 + wid * 32 + l16) * 128;
        u16* pp1 = pp0 + 16 * 128;
        #pragma unroll
        for (int e = 0; e < 8; ++e) {
            u16x4 v0, v1;
            #pragma unroll
            for (int r = 0; r < 4; ++r) { v0[r] = f2bf(o0[e][r]); v1[r] = f2bf(o1[e][r]); }
            *(u16x4*)&pp0[e * 16 + g * 4] = v0;
            *(u16x4*)&pp1[e * 16 + g * 4] = v1;
        }
        if (g == 0) {
            pml[(size_t)slot * 128 + wid * 32 + l16] = l0;
            pml[(size_t)slot * 128 + wid * 32 + 16 + l16] = l1;
        }
    }
}

// ---------------------------------------------------------------------------
// Kernel 3: merge split-K partials (qb >= 2). Plain sums (no max logic).
// ---------------------------------------------------------------------------
__global__ __launch_bounds__(256) void merge6(
    const u16* __restrict__ po, const float* __restrict__ pml,
    float* __restrict__ out)
{
    int gid = blockIdx.x * 256 + threadIdx.x;   // 491,520 total
    int colg = gid & 31;
    int rowid = gid >> 5;                        // [0, 15360)
    int b = rowid / 3840;
    int rr = rowid - b * 3840;
    int qb = (rr >> 7) + 2;
    int qr = rr & 127;
    int u = qb >> 1;
    int nch = u + 1;
    int slot0 = b * 272 + u * (u + 1) + (qb & 1) * (u + 1);

    float den = 0.f;
    f32x4 num = {0.f, 0.f, 0.f, 0.f};
    #pragma unroll 1
    for (int cc = 0; cc < nch; ++cc) {
        den += pml[(size_t)(slot0 + cc) * 128 + qr];
        u16x4 pv = *(const u16x4*)&po[((size_t)(slot0 + cc) * 128 + qr) * 128 + colg * 4];
        #pragma unroll
        for (int j = 0; j < 4; ++j) num[j] += bf2f(pv[j]);
    }
    float inv = 1.0f / den;
    f32x4 res = { num[0] * inv, num[1] * inv, num[2] * inv, num[3] * inv };
    *(f32x4*)&out[((size_t)b * 4096 + qb * 128 + qr) * 128 + colg * 4] = res;
}

extern "C" void kernel_launch(void* const* d_in, const int* in_sizes, int n_in,
                              void* d_out, int out_size, void* d_ws, size_t ws_size,
                              hipStream_t stream) {
    (void)in_sizes; (void)n_in; (void)out_size;
    const float* x  = (const float*)d_in[0];
    const float* Wq = (const float*)d_in[1];
    const float* Wk = (const float*)d_in[2];
    const float* Wv = (const float*)d_in[3];
    float* out = (float*)d_out;

    // Layout: [Qf Kf Vf | scratch]; scratch aliased:
    //   phase 1 (prep/qkv): xf (16 MB) + wf (0.4 MB)
    //   phase 2 (attn/merge): po (35.65 MB) + pml (0.56 MB)
    u16* Qf = (u16*)d_ws;                    // 2,097,152 u16 each
    u16* Kf = Qf + 2097152;
    u16* Vf = Kf + 2097152;
    u16* xf = Vf + 2097152;                  // 8,388,608 u16
    u16* wf = xf + 8388608;                  //   196,608 u16
    u16* po = xf;                            // alias (xf/wf dead after qkv2)
    float* pml = (float*)(po + (size_t)1088 * 128 * 128);

    const size_t fixed_b = (size_t)3 * 2097152 * 2;                   // 12,582,912
    const size_t part_b  = (size_t)1088 * 128 * (128 * 2 + 4);        // 36,208,640
    const int split = (ws_size >= fixed_b + part_b) ? 1 : 0;          // 48.8 MB

    prep_all<<<1120, 256, 0, stream>>>(x, Wq, Wk, Wv, xf, wf);
    qkv2<<<dim3(256, 3), 256, 0, stream>>>(xf, wf, Qf, Kf, Vf);
    attn10<<<split ? 1088 : 128, 256, 0, stream>>>(Qf, Kf, Vf, out, po, pml, split);
    if (split) merge6<<<1920, 256, 0, stream>>>(po, pml, out);
}

// Round 19
// 79.236 us; speedup vs baseline: 1.2767x; 1.0449x over previous
//
#include <hip/hip_runtime.h>

typedef __bf16 bf16x8 __attribute__((ext_vector_type(8)));
typedef float f32x4 __attribute__((ext_vector_type(4)));
typedef unsigned short u16;
typedef unsigned int u32;
typedef u16 u16x8 __attribute__((ext_vector_type(8)));
typedef u16 u16x4 __attribute__((ext_vector_type(4)));
typedef u32 u32x4 __attribute__((ext_vector_type(4)));

__device__ __forceinline__ u16 f2bf(float f) {
    u32 u = __builtin_bit_cast(u32, f);
    u += 0x7fffu + ((u >> 16) & 1u);   // RNE
    return (u16)(u >> 16);
}
__device__ __forceinline__ float bf2f(u16 v) {
    return __builtin_bit_cast(float, (u32)v << 16);
}
__device__ __forceinline__ u32 cvtpk(float a, float b) {   // lo=bf16(a), hi=bf16(b)
    u32 d;
    asm("v_cvt_pk_bf16_f32 %0, %1, %2" : "=v"(d) : "v"(a), "v"(b));
    return d;
}
__device__ __forceinline__ f32x4 mfma16(u16x8 a, u16x8 b, f32x4 c) {
    return __builtin_amdgcn_mfma_f32_16x16x32_bf16(
        __builtin_bit_cast(bf16x8, a), __builtin_bit_cast(bf16x8, b), c, 0, 0, 0);
}

#define GLOAD16(SRC, DST)                                                     \
    __builtin_amdgcn_global_load_lds(                                         \
        (const __attribute__((address_space(1))) unsigned int*)(SRC),         \
        (__attribute__((address_space(3))) unsigned int*)(DST), 16, 0, 0)

// chunk-XOR LDS addressing for a [16][128] u16 tile (16B chunks, XOR row into chunk)
__device__ __forceinline__ int ldsAddr(int r, int c) {       // u16 index
    return r * 128 + (((c >> 3) ^ (r & 7)) << 3) + (c & 7);
}

// ---------------------------------------------------------------------------
// Kernel 0: fused prep. Blocks [0,1024): x fp32 -> xf frag-major bf16.
// Blocks [1024,1120): W fp32 [512][128] -> Wf frag-major bf16
// (Wq pre-scaled by 1/sqrt(128)*log2(e) for log2-domain softmax).
// ---------------------------------------------------------------------------
__global__ __launch_bounds__(256) void prep_all(
    const float* __restrict__ x,
    const float* __restrict__ Wq, const float* __restrict__ Wk,
    const float* __restrict__ Wv,
    u16* __restrict__ xf, u16* __restrict__ wf)
{
    __shared__ u16 T[16 * 512];
    const int t = threadIdx.x;
    if (blockIdx.x < 1024) {
        const int rb = blockIdx.x;
        const int row = t >> 4, colb = (t & 15) * 32;
        const float* src = x + (size_t)(rb * 16 + row) * 512 + colb;
        #pragma unroll
        for (int i = 0; i < 4; ++i) {
            float4 va = *(const float4*)(src + i * 8);
            float4 vb = *(const float4*)(src + i * 8 + 4);
            u16x8 v;
            v[0] = f2bf(va.x); v[1] = f2bf(va.y); v[2] = f2bf(va.z); v[3] = f2bf(va.w);
            v[4] = f2bf(vb.x); v[5] = f2bf(vb.y); v[6] = f2bf(vb.z); v[7] = f2bf(vb.w);
            int chunk = ((colb >> 3) + i) ^ (row & 7);
            *(u16x8*)&T[row * 512 + chunk * 8] = v;
        }
        __syncthreads();
        #pragma unroll
        for (int ii = 0; ii < 4; ++ii) {
            int flatF = ii * 256 + t;
            int ds = flatF >> 6, lane = flatF & 63;
            int l16 = lane & 15, g = lane >> 4;
            int chunk = (4 * ds + g) ^ (l16 & 7);
            u16x8 v = *(const u16x8*)&T[l16 * 512 + chunk * 8];
            *(u16x8*)&xf[(((size_t)rb * 16 + ds) * 64 + lane) * 8] = v;
        }
    } else {
        int flat = (blockIdx.x - 1024) * 256 + t;      // [0, 24576)
        int widx = flat >> 13, rem = flat & 8191;
        int n = rem >> 10, ds = (rem >> 6) & 15, lane = rem & 63;
        int l16 = lane & 15, g = lane >> 4;
        const float* W = (widx == 0) ? Wq : (widx == 1 ? Wk : Wv);
        const float sc = (widx == 0) ? (0.08838834764831845f * 1.4426950408889634f) : 1.0f;
        u16x8 v;
        #pragma unroll
        for (int j = 0; j < 8; ++j)
            v[j] = f2bf(W[(size_t)(ds * 32 + 8 * g + j) * 128 + n * 16 + l16] * sc);
        *(u16x8*)&wf[(size_t)flat * 8] = v;
    }
}

// ---------------------------------------------------------------------------
// Kernel 1: QKV GEMM with LDS-staged W slices (round-13, measured good).
// Block = 4 waves x 16 rows; grid (256, 3) = 768 blocks -> 3 blocks/CU.
// ---------------------------------------------------------------------------
__global__ __launch_bounds__(256, 3) void qkv2(
    const u16* __restrict__ xf, const u16* __restrict__ wf,
    u16* __restrict__ Qf, u16* __restrict__ Kf, u16* __restrict__ Vf)
{
    __shared__ u16 Wbuf[2][4096];    // [buf][n*64+lane -> 8 u16]  (8 KB each)
    __shared__ u16 T4[4][16 * 128];
    const int tid = threadIdx.x, lane = tid & 63, wid = tid >> 6;
    const int g = lane >> 4, l16 = lane & 15;
    const int widx = blockIdx.y;
    const int rbg = blockIdx.x * 4 + wid;        // 16-row block [0,1024)
    const u16* WfB = wf + (size_t)widx * 65536;
    u16* T = T4[wid];

    GLOAD16(WfB + (size_t)((wid * 16 + 0) * 64 + lane) * 8,
            Wbuf[0] + (wid * 64 + lane) * 8);
    GLOAD16(WfB + (size_t)(((wid + 4) * 16 + 0) * 64 + lane) * 8,
            Wbuf[0] + ((wid + 4) * 64 + lane) * 8);

    const f32x4 fz = {0.f, 0.f, 0.f, 0.f};
    f32x4 acc[8];
    #pragma unroll
    for (int n = 0; n < 8; ++n) acc[n] = fz;

    u16x8 a_cur = *(const u16x8*)&xf[(((size_t)rbg * 16 + 0) * 64 + lane) * 8];
    __syncthreads();                              // slice 0 staged

    #pragma unroll 1
    for (int ds = 0; ds < 16; ++ds) {
        u16x8 a_next;
        if (ds + 1 < 16) {
            const int nds = ds + 1, bb = nds & 1;
            GLOAD16(WfB + (size_t)((wid * 16 + nds) * 64 + lane) * 8,
                    Wbuf[bb] + (wid * 64 + lane) * 8);
            GLOAD16(WfB + (size_t)(((wid + 4) * 16 + nds) * 64 + lane) * 8,
                    Wbuf[bb] + ((wid + 4) * 64 + lane) * 8);
            a_next = *(const u16x8*)&xf[(((size_t)rbg * 16 + nds) * 64 + lane) * 8];
        }
        const u16* Wl = Wbuf[ds & 1];
        #pragma unroll
        for (int n = 0; n < 8; ++n) {
            u16x8 b = *(const u16x8*)&Wl[(n * 64 + lane) * 8];
            acc[n] = mfma16(a_cur, b, acc[n]);
        }
        __syncthreads();
        if (ds + 1 < 16) a_cur = a_next;
    }

    #pragma unroll
    for (int n = 0; n < 8; ++n) {
        #pragma unroll
        for (int r = 0; r < 4; ++r)
            T[ldsAddr(4 * g + r, n * 16 + l16)] = f2bf(acc[n][r]);
    }
    if (widx < 2) {
        u16* dst = (widx == 0) ? Qf : Kf;
        #pragma unroll
        for (int ds = 0; ds < 4; ++ds) {
            int chunk = (4 * ds + g) ^ (l16 & 7);
            u16x8 v = *(const u16x8*)&T[l16 * 128 + chunk * 8];
            *(u16x8*)&dst[(((size_t)rbg * 4 + ds) * 64 + lane) * 8] = v;
        }
    } else {
        const int kb = rbg >> 2, ksel = (rbg >> 1) & 1, g0 = (rbg & 1) * 2;
        #pragma unroll
        for (int s = 0; s < 4; ++s) {
            int flat = s * 64 + lane;
            int e = flat >> 5, gg = (flat >> 4) & 1, l16p = flat & 15;
            u16x8 v;
            #pragma unroll
            for (int j = 0; j < 8; ++j)
                v[j] = T[ldsAddr(8 * gg + j, e * 16 + l16p)];
            *(u16x8*)&Vf[((((size_t)kb * 2 + ksel) * 8 + e) * 64
                          + (g0 + gg) * 16 + l16p) * 8] = v;
        }
    }
}

// ---------------------------------------------------------------------------
// Kernel 2: block-cooperative causal flash attention (round-12 config, exact;
// measured best = 45.7us). Block = 4 waves x 32 q-rows; one (qb, 256-key
// chunk) job; 1088 blocks. K/V double-buffered 64KB LDS -> 2 blocks/CU.
// MEASURED WALLS: >2 blocks/CU thrashes per-XCD L2 (r7/r8/r14); counted-vmcnt
// pipelining adds nothing at this occupancy (r16-r18) — implicit inter-block
// overlap already covers the barrier drain. Unnormalized log2 softmax.
// ---------------------------------------------------------------------------
__global__ __launch_bounds__(256, 2) void attn6(
    const u16* __restrict__ Qf, const u16* __restrict__ Kf,
    const u16* __restrict__ Vf, float* __restrict__ out,
    u16* __restrict__ po, float* __restrict__ pml, int split)
{
    __shared__ u16 lds[2][16384];   // [buf][ K 16KB | V 16KB ]
    const int tid = threadIdx.x, lane = tid & 63, wid = tid >> 6;
    const int g = lane >> 4, l16 = lane & 15;

    int b, qb, c, u;
    if (split) {
        const int xcd = blockIdx.x & 7;        // XCD pair {2b,2b+1} -> batch b
        b = xcd >> 1;
        int jb = 271 - ((xcd & 1) * 136 + (blockIdx.x >> 3));   // longest-first
        u = 0;
        while ((u + 1) * (u + 2) <= jb) ++u;   // u(u+1) <= jb < (u+1)(u+2)
        int r = jb - u * (u + 1);
        int hi = (r >= u + 1) ? 1 : 0;
        qb = 2 * u + hi;
        c = r - hi * (u + 1);
    } else {
        b = blockIdx.x & 3;
        qb = blockIdx.x >> 2;
        c = 0; u = 0;
    }
    const int q0 = qb * 128 + wid * 32;        // wave's first q row
    const int k_lo = c * 256;
    const int k_hi = min(k_lo + (split ? 256 : 4096), qb * 128 + 128);
    const int nch = u + 1;
    const int wklen = q0 + 32;                 // wave needs tiles with k0 < wklen

    // prologue: stage tile 0 + load Q fragments (overlapped)
    {
        const u16* src;
        if (wid < 2) src = Kf + (size_t)(b * 256 + (k_lo >> 4)) * 2048 + wid * 4096;
        else         src = Vf + (size_t)(b * 64 + (k_lo >> 6)) * 8192 + (wid - 2) * 4096;
        u16* dst = &lds[0][wid * 4096];
        #pragma unroll
        for (int j = 0; j < 8; ++j)
            GLOAD16(src + j * 512 + lane * 8, dst + j * 512);
    }
    const int rbq = b * 256 + qb * 8 + wid * 2;
    u16x8 qf0[4], qf1[4];
    #pragma unroll
    for (int ds = 0; ds < 4; ++ds) {
        qf0[ds] = *(const u16x8*)&Qf[(((size_t)rbq * 4 + ds) * 64 + lane) * 8];
        qf1[ds] = *(const u16x8*)&Qf[(((size_t)(rbq + 1) * 4 + ds) * 64 + lane) * 8];
    }

    const f32x4 fz = {0.f, 0.f, 0.f, 0.f};
    f32x4 o0[8], o1[8];
    #pragma unroll
    for (int e = 0; e < 8; ++e) { o0[e] = fz; o1[e] = fz; }
    float l0 = 0.f, l1 = 0.f;                  // per-lane partial denominators

    const int srcA = l16 + ((g & 1) << 5);
    const int srcB = srcA + 16;
    const bool hiSel = (g >= 2);

    __syncthreads();                            // tile 0 staged

    int bufsel = 0;
    for (int k0 = k_lo; k0 < k_hi; k0 += 64) {
        // ---- prefetch next tile into other buffer ----
        if (k0 + 64 < k_hi) {
            const u16* src;
            if (wid < 2) src = Kf + (size_t)(b * 256 + ((k0 + 64) >> 4)) * 2048 + wid * 4096;
            else         src = Vf + (size_t)(b * 64 + ((k0 + 64) >> 6)) * 8192 + (wid - 2) * 4096;
            u16* dst = &lds[bufsel ^ 1][wid * 4096];
            #pragma unroll
            for (int j = 0; j < 8; ++j)
                GLOAD16(src + j * 512 + lane * 8, dst + j * 512);
        }
        if (k0 < wklen) {
            const u16* Kl = &lds[bufsel][0];
            const u16* Vl = &lds[bufsel][8192];
            // ---- S^T = K * Q^T for both q-halves (K frags shared) ----
            f32x4 st0[4], st1[4];
            __builtin_amdgcn_s_setprio(1);
            #pragma unroll
            for (int kt = 0; kt < 4; ++kt) {
                st0[kt] = fz; st1[kt] = fz;
                #pragma unroll
                for (int ds = 0; ds < 4; ++ds) {
                    u16x8 kf = *(const u16x8*)&Kl[(kt * 4 + ds) * 512 + lane * 8];
                    st0[kt] = mfma16(kf, qf0[ds], st0[kt]);
                    st1[kt] = mfma16(kf, qf1[ds], st1[kt]);
                }
            }
            __builtin_amdgcn_s_setprio(0);
            // ---- causal mask (diagonal tiles only), per half ----
            if (k0 + 63 > q0) {
                int qg = q0 + l16;
                #pragma unroll
                for (int kt = 0; kt < 4; ++kt)
                    #pragma unroll
                    for (int r = 0; r < 4; ++r)
                        if (k0 + kt * 16 + g * 4 + r > qg) st0[kt][r] = -1e30f;
            }
            if (k0 + 63 > q0 + 16) {
                int qg = q0 + 16 + l16;
                #pragma unroll
                for (int kt = 0; kt < 4; ++kt)
                    #pragma unroll
                    for (int r = 0; r < 4; ++r)
                        if (k0 + kt * 16 + g * 4 + r > qg) st1[kt][r] = -1e30f;
            }
            // ---- unnormalized softmax: p = exp2(st), per-lane l accumulate ----
            u32 pk0[4][2], pk1[4][2];
            #pragma unroll
            for (int kt = 0; kt < 4; ++kt) {
                float p0 = exp2f(st0[kt][0]), p1 = exp2f(st0[kt][1]);
                float p2 = exp2f(st0[kt][2]), p3 = exp2f(st0[kt][3]);
                l0 += (p0 + p1) + (p2 + p3);
                pk0[kt][0] = cvtpk(p0, p1);
                pk0[kt][1] = cvtpk(p2, p3);
                float q0v = exp2f(st1[kt][0]), q1v = exp2f(st1[kt][1]);
                float q2v = exp2f(st1[kt][2]), q3v = exp2f(st1[kt][3]);
                l1 += (q0v + q1v) + (q2v + q3v);
                pk1[kt][0] = cvtpk(q0v, q1v);
                pk1[kt][1] = cvtpk(q2v, q3v);
            }
            // ---- P redistribute (in-register) + O^T += V^T * P^T ----
            #pragma unroll
            for (int ksel = 0; ksel < 2; ++ksel) {
                u32 a0 = __shfl((int)pk0[2 * ksel][0], srcA), b0 = __shfl((int)pk0[2 * ksel + 1][0], srcA);
                u32 a1 = __shfl((int)pk0[2 * ksel][1], srcA), b1 = __shfl((int)pk0[2 * ksel + 1][1], srcA);
                u32 a2 = __shfl((int)pk0[2 * ksel][0], srcB), b2 = __shfl((int)pk0[2 * ksel + 1][0], srcB);
                u32 a3 = __shfl((int)pk0[2 * ksel][1], srcB), b3 = __shfl((int)pk0[2 * ksel + 1][1], srcB);
                u32x4 d0 = { hiSel ? b0 : a0, hiSel ? b1 : a1, hiSel ? b2 : a2, hiSel ? b3 : a3 };
                u16x8 pf0 = __builtin_bit_cast(u16x8, d0);
                u32 c0 = __shfl((int)pk1[2 * ksel][0], srcA), e0 = __shfl((int)pk1[2 * ksel + 1][0], srcA);
                u32 c1 = __shfl((int)pk1[2 * ksel][1], srcA), e1 = __shfl((int)pk1[2 * ksel + 1][1], srcA);
                u32 c2 = __shfl((int)pk1[2 * ksel][0], srcB), e2 = __shfl((int)pk1[2 * ksel + 1][0], srcB);
                u32 c3 = __shfl((int)pk1[2 * ksel][1], srcB), e3 = __shfl((int)pk1[2 * ksel + 1][1], srcB);
                u32x4 d1 = { hiSel ? e0 : c0, hiSel ? e1 : c1, hiSel ? e2 : c2, hiSel ? e3 : c3 };
                u16x8 pf1 = __builtin_bit_cast(u16x8, d1);
                __builtin_amdgcn_s_setprio(1);
                #pragma unroll
                for (int e = 0; e < 8; ++e) {
                    u16x8 vf = *(const u16x8*)&Vl[(ksel * 8 + e) * 512 + lane * 8];
                    o0[e] = mfma16(vf, pf0, o0[e]);
                    o1[e] = mfma16(vf, pf1, o1[e]);
                }
                __builtin_amdgcn_s_setprio(0);
            }
        }
        __syncthreads();   // drains gload_lds (vmcnt) + lds reads; buffers swap safely
        bufsel ^= 1;
    }

    // reduce per-lane denominators across the 4 k-groups (once per block)
    l0 += __shfl_xor(l0, 16); l0 += __shfl_xor(l0, 32);
    l1 += __shfl_xor(l1, 16); l1 += __shfl_xor(l1, 32);

    if (nch == 1) {
        float inv0 = 1.0f / l0, inv1 = 1.0f / l1;
        float* op0 = out + ((size_t)b * 4096 + q0 + l16) * 128;
        float* op1 = out + ((size_t)b * 4096 + q0 + 16 + l16) * 128;
        #pragma unroll
        for (int e = 0; e < 8; ++e) {
            f32x4 v0 = o0[e], v1 = o1[e];
            #pragma unroll
            for (int r = 0; r < 4; ++r) { v0[r] *= inv0; v1[r] *= inv1; }
            *(f32x4*)&op0[e * 16 + g * 4] = v0;
            *(f32x4*)&op1[e * 16 + g * 4] = v1;
        }
    } else {
        const int slot = b * 272 + u * (u + 1) + (qb & 1) * (u + 1) + c;
        u16* pp0 = po + ((size_t)slot * 128 + wid * 32 + l16) * 128;
        u16* pp1 = pp0 + 16 * 128;
        #pragma unroll
        for (int e = 0; e < 8; ++e) {
            u16x4 v0, v1;
            #pragma unroll
            for (int r = 0; r < 4; ++r) { v0[r] = f2bf(o0[e][r]); v1[r] = f2bf(o1[e][r]); }
            *(u16x4*)&pp0[e * 16 + g * 4] = v0;
            *(u16x4*)&pp1[e * 16 + g * 4] = v1;
        }
        if (g == 0) {
            pml[(size_t)slot * 128 + wid * 32 + l16] = l0;
            pml[(size_t)slot * 128 + wid * 32 + 16 + l16] = l1;
        }
    }
}

// ---------------------------------------------------------------------------
// Kernel 3: merge split-K partials (qb >= 2). Plain sums (no max logic).
// ---------------------------------------------------------------------------
__global__ __launch_bounds__(256) void merge6(
    const u16* __restrict__ po, const float* __restrict__ pml,
    float* __restrict__ out)
{
    int gid = blockIdx.x * 256 + threadIdx.x;   // 491,520 total
    int colg = gid & 31;
    int rowid = gid >> 5;                        // [0, 15360)
    int b = rowid / 3840;
    int rr = rowid - b * 3840;
    int qb = (rr >> 7) + 2;
    int qr = rr & 127;
    int u = qb >> 1;
    int nch = u + 1;
    int slot0 = b * 272 + u * (u + 1) + (qb & 1) * (u + 1);

    float den = 0.f;
    f32x4 num = {0.f, 0.f, 0.f, 0.f};
    #pragma unroll 1
    for (int cc = 0; cc < nch; ++cc) {
        den += pml[(size_t)(slot0 + cc) * 128 + qr];
        u16x4 pv = *(const u16x4*)&po[((size_t)(slot0 + cc) * 128 + qr) * 128 + colg * 4];
        #pragma unroll
        for (int j = 0; j < 4; ++j) num[j] += bf2f(pv[j]);
    }
    float inv = 1.0f / den;
    f32x4 res = { num[0] * inv, num[1] * inv, num[2] * inv, num[3] * inv };
    *(f32x4*)&out[((size_t)b * 4096 + qb * 128 + qr) * 128 + colg * 4] = res;
}

extern "C" void kernel_launch(void* const* d_in, const int* in_sizes, int n_in,
                              void* d_out, int out_size, void* d_ws, size_t ws_size,
                              hipStream_t stream) {
    (void)in_sizes; (void)n_in; (void)out_size;
    const float* x  = (const float*)d_in[0];
    const float* Wq = (const float*)d_in[1];
    const float* Wk = (const float*)d_in[2];
    const float* Wv = (const float*)d_in[3];
    float* out = (float*)d_out;

    // Layout: [Qf Kf Vf | scratch]; scratch aliased:
    //   phase 1 (prep/qkv): xf (16 MB) + wf (0.4 MB)
    //   phase 2 (attn/merge): po (35.65 MB) + pml (0.56 MB)
    u16* Qf = (u16*)d_ws;                    // 2,097,152 u16 each
    u16* Kf = Qf + 2097152;
    u16* Vf = Kf + 2097152;
    u16* xf = Vf + 2097152;                  // 8,388,608 u16
    u16* wf = xf + 8388608;                  //   196,608 u16
    u16* po = xf;                            // alias (xf/wf dead after qkv2)
    float* pml = (float*)(po + (size_t)1088 * 128 * 128);

    const size_t fixed_b = (size_t)3 * 2097152 * 2;                   // 12,582,912
    const size_t part_b  = (size_t)1088 * 128 * (128 * 2 + 4);        // 36,208,640
    const int split = (ws_size >= fixed_b + part_b) ? 1 : 0;          // 48.8 MB

    prep_all<<<1120, 256, 0, stream>>>(x, Wq, Wk, Wv, xf, wf);
    qkv2<<<dim3(256, 3), 256, 0, stream>>>(xf, wf, Qf, Kf, Vf);
    attn6<<<split ? 1088 : 128, 256, 0, stream>>>(Qf, Kf, Vf, out, po, pml, split);
    if (split) merge6<<<1920, 256, 0, stream>>>(po, pml, out);
}